// Round 1
// baseline (2108.569 us; speedup 1.0000x reference)
//
#include <hip/hip_runtime.h>

#define N_PTS 131072
#define K_CODES 1024
#define DIM 64
#define DECAYF 0.99f
#define OMDF 0.01f
#define EPSF 1e-5f

// ---- d_out layout (float elements, reference return order) ----
#define OUT_ZQ      0                  // [N, D]
#define OUT_LOSS    8388608            // scalar
#define OUT_IDX     8388609            // [N]
#define OUT_NEWEMB  8519681            // [K, D]
#define OUT_NEWCS   8585217            // [K]
#define OUT_NEWEMA  8586241            // [K, D]

// ---- ws layout (float elements) ----
#define WS_LOSS     0                  // 1 (padded to 64)
#define WS_COUNTS   64                 // K
#define WS_EMBSUM   1088               // K*D
#define WS_CS       66624              // K
#define WS_ENORM    67648              // K
#define WS_IDX      68672              // N ints
// memset-zero region covers [0, WS_CS) floats

__global__ __launch_bounds__(256) void enorm_kernel(const float* __restrict__ E,
                                                    float* __restrict__ enorm) {
    int k = blockIdx.x * blockDim.x + threadIdx.x;
    if (k < K_CODES) {
        const float4* e4 = (const float4*)(E + (size_t)k * DIM);
        float s = 0.f;
#pragma unroll
        for (int i = 0; i < 16; ++i) {
            float4 v = e4[i];
            s += v.x * v.x + v.y * v.y + v.z * v.z + v.w * v.w;
        }
        enorm[k] = s;
    }
}

// One thread per z-row. E staged in LDS in 64-code chunks; all lanes read the
// same LDS address per step (broadcast, conflict-free). score = ||e||^2 - 2 z.e
// (the ||z||^2 term is row-constant and argmin-invariant).
__global__ __launch_bounds__(256) void argmin_kernel(const float* __restrict__ z,
                                                     const float* __restrict__ E,
                                                     const float* __restrict__ enorm,
                                                     float* __restrict__ out_idx_f,
                                                     int* __restrict__ idx_i) {
    __shared__ float se[64 * DIM];   // 16 KB chunk of codes
    __shared__ float sn[64];         // chunk norms

    int row = blockIdx.x * 256 + threadIdx.x;
    float zr[DIM];
    {
        const float4* z4 = (const float4*)(z + (size_t)row * DIM);
#pragma unroll
        for (int i = 0; i < 16; ++i) {
            float4 v = z4[i];
            zr[4 * i + 0] = v.x; zr[4 * i + 1] = v.y;
            zr[4 * i + 2] = v.z; zr[4 * i + 3] = v.w;
        }
    }

    float best = INFINITY;
    int bidx = 0;

    for (int c = 0; c < K_CODES; c += 64) {
        __syncthreads();
        {   // cooperative stage: 64 codes * 64 floats = 1024 float4, 4 per thread
            const float4* E4 = (const float4*)(E + (size_t)c * DIM);
            float4* s4 = (float4*)se;
#pragma unroll
            for (int i = 0; i < 4; ++i)
                s4[threadIdx.x + 256 * i] = E4[threadIdx.x + 256 * i];
            if (threadIdx.x < 64) sn[threadIdx.x] = enorm[c + threadIdx.x];
        }
        __syncthreads();

#pragma unroll 2
        for (int k = 0; k < 64; ++k) {
            const float4* er4 = (const float4*)(se + k * DIM);
            float d0 = 0.f, d1 = 0.f, d2 = 0.f, d3 = 0.f;
#pragma unroll
            for (int i = 0; i < 16; ++i) {
                float4 ev = er4[i];
                d0 += zr[4 * i + 0] * ev.x;
                d1 += zr[4 * i + 1] * ev.y;
                d2 += zr[4 * i + 2] * ev.z;
                d3 += zr[4 * i + 3] * ev.w;
            }
            float score = sn[k] - 2.f * ((d0 + d1) + (d2 + d3));
            if (score < best) { best = score; bidx = c + k; }
        }
    }

    out_idx_f[row] = (float)bidx;
    idx_i[row] = bidx;
}

// Gather z_q, write it, accumulate commitment loss, counts, embed_sum.
__global__ __launch_bounds__(256) void gather_stats_kernel(const float* __restrict__ z,
                                                           const float* __restrict__ E,
                                                           const int* __restrict__ idx,
                                                           float* __restrict__ zq_out,
                                                           float* __restrict__ loss_ws,
                                                           float* __restrict__ counts,
                                                           float* __restrict__ embsum) {
    int row = blockIdx.x * 256 + threadIdx.x;
    int k = idx[row];
    const float4* z4 = (const float4*)(z + (size_t)row * DIM);
    const float4* e4 = (const float4*)(E + (size_t)k * DIM);
    float4* o4 = (float4*)(zq_out + (size_t)row * DIM);
    float* es = embsum + (size_t)k * DIM;

    float s = 0.f;
#pragma unroll
    for (int i = 0; i < 16; ++i) {
        float4 zv = z4[i];
        float4 ev = e4[i];
        o4[i] = ev;
        float dx = zv.x - ev.x, dy = zv.y - ev.y;
        float dz = zv.z - ev.z, dw = zv.w - ev.w;
        s += dx * dx + dy * dy + dz * dz + dw * dw;
        atomicAdd(&es[4 * i + 0], zv.x);
        atomicAdd(&es[4 * i + 1], zv.y);
        atomicAdd(&es[4 * i + 2], zv.z);
        atomicAdd(&es[4 * i + 3], zv.w);
    }
    atomicAdd(&counts[k], 1.0f);

    // block-reduce the squared-diff sum, one atomic per block
    __shared__ float red[256];
    red[threadIdx.x] = s;
    __syncthreads();
    for (int st = 128; st > 0; st >>= 1) {
        if (threadIdx.x < st) red[threadIdx.x] += red[threadIdx.x + st];
        __syncthreads();
    }
    if (threadIdx.x == 0) atomicAdd(loss_ws, red[0]);
}

// One block of 1024: new_cluster_size, n (block reduce), cs, final loss.
__global__ __launch_bounds__(1024) void ema_small_kernel(const float* __restrict__ cluster_size,
                                                         const float* __restrict__ counts,
                                                         float* __restrict__ ncs_out,
                                                         float* __restrict__ cs_ws,
                                                         const float* __restrict__ loss_ws,
                                                         float* __restrict__ loss_out) {
    int k = threadIdx.x;
    float ncs = cluster_size[k] * DECAYF + OMDF * counts[k];
    ncs_out[k] = ncs;

    __shared__ float red[1024];
    red[k] = ncs;
    __syncthreads();
    for (int st = 512; st > 0; st >>= 1) {
        if (k < st) red[k] += red[k + st];
        __syncthreads();
    }
    float n = red[0];
    float cs = (ncs + EPSF) / (n + (float)K_CODES * EPSF) * n;
    cs_ws[k] = cs;
    if (k == 0) loss_out[0] = loss_ws[0] * (1.0f / ((float)N_PTS * (float)DIM));
}

__global__ __launch_bounds__(256) void ema2_kernel(const float* __restrict__ ema,
                                                   const float* __restrict__ embsum,
                                                   const float* __restrict__ cs_ws,
                                                   float* __restrict__ newema_out,
                                                   float* __restrict__ newemb_out) {
    int i = blockIdx.x * 256 + threadIdx.x;   // over K*D
    float nes = ema[i] * DECAYF + OMDF * embsum[i];
    newema_out[i] = nes;
    newemb_out[i] = nes / cs_ws[i >> 6];
}

extern "C" void kernel_launch(void* const* d_in, const int* in_sizes, int n_in,
                              void* d_out, int out_size, void* d_ws, size_t ws_size,
                              hipStream_t stream) {
    const float* z            = (const float*)d_in[0];
    const float* E            = (const float*)d_in[1];
    const float* cluster_size = (const float*)d_in[2];
    const float* ema          = (const float*)d_in[3];
    float* out = (float*)d_out;
    float* ws  = (float*)d_ws;

    // zero the accumulators (loss, counts, embed_sum) — ws is poisoned 0xAA
    hipMemsetAsync(ws, 0, (size_t)WS_CS * sizeof(float), stream);

    enorm_kernel<<<4, 256, 0, stream>>>(E, ws + WS_ENORM);

    argmin_kernel<<<N_PTS / 256, 256, 0, stream>>>(z, E, ws + WS_ENORM,
                                                   out + OUT_IDX,
                                                   (int*)(ws + WS_IDX));

    gather_stats_kernel<<<N_PTS / 256, 256, 0, stream>>>(z, E,
                                                         (const int*)(ws + WS_IDX),
                                                         out + OUT_ZQ,
                                                         ws + WS_LOSS,
                                                         ws + WS_COUNTS,
                                                         ws + WS_EMBSUM);

    ema_small_kernel<<<1, 1024, 0, stream>>>(cluster_size, ws + WS_COUNTS,
                                             out + OUT_NEWCS, ws + WS_CS,
                                             ws + WS_LOSS, out + OUT_LOSS);

    ema2_kernel<<<K_CODES * DIM / 256, 256, 0, stream>>>(ema, ws + WS_EMBSUM,
                                                         ws + WS_CS,
                                                         out + OUT_NEWEMA,
                                                         out + OUT_NEWEMB);
}

// Round 2
// 781.957 us; speedup vs baseline: 2.6965x; 2.6965x over previous
//
#include <hip/hip_runtime.h>

#define N_PTS 131072
#define K_CODES 1024
#define DIM 64
#define DECAYF 0.99f
#define OMDF 0.01f
#define EPSF 1e-5f

// ---- d_out layout (float elements, reference return order) ----
#define OUT_ZQ      0                  // [N, D]
#define OUT_LOSS    8388608            // scalar
#define OUT_IDX     8388609            // [N] (indices as floats)
#define OUT_NEWEMB  8519681            // [K, D]
#define OUT_NEWCS   8585217            // [K]
#define OUT_NEWEMA  8586241            // [K, D]

// ---- ws layout (float elements) ----
#define WS_COUNTS   0                  // K floats (memset to 0 each launch)
#define WS_START    1024               // K ints
#define WS_CURSOR   2048               // K ints
#define WS_CS       3072               // K floats
#define WS_ENORM    4096               // K floats
#define WS_LOSSARR  5120               // K floats (per-code SSE partials)
#define WS_ORDER    6144               // N ints
// total: 6144 + 131072 floats = 549 KB

__global__ __launch_bounds__(256) void enorm_kernel(const float* __restrict__ E,
                                                    float* __restrict__ enorm) {
    int k = blockIdx.x * blockDim.x + threadIdx.x;
    if (k < K_CODES) {
        const float4* e4 = (const float4*)(E + (size_t)k * DIM);
        float s = 0.f;
#pragma unroll
        for (int i = 0; i < 16; ++i) {
            float4 v = e4[i];
            s += v.x * v.x + v.y * v.y + v.z * v.z + v.w * v.w;
        }
        enorm[k] = s;
    }
}

// 128 threads/block, 2 rows/thread -> 256 rows/block, 512 blocks.
// E staged in LDS in 64-code chunks; broadcast ds_read_b128 feeds BOTH rows
// (halves LDS instruction count vs 1 row/thread). score = ||e||^2 - 2 z.e.
__global__ __launch_bounds__(128) void argmin_kernel(const float* __restrict__ z,
                                                     const float* __restrict__ E,
                                                     const float* __restrict__ enorm,
                                                     float* __restrict__ out_idx_f,
                                                     float* __restrict__ counts) {
    __shared__ float4 se4[64 * 16];   // 16 KB chunk of codes
    __shared__ float sn[64];

    int row0 = blockIdx.x * 256 + threadIdx.x;
    int row1 = row0 + 128;

    float4 zr0[16], zr1[16];
    const float4* z4 = (const float4*)z;
#pragma unroll
    for (int i = 0; i < 16; ++i) zr0[i] = z4[(size_t)row0 * 16 + i];
#pragma unroll
    for (int i = 0; i < 16; ++i) zr1[i] = z4[(size_t)row1 * 16 + i];

    float best0 = INFINITY, best1 = INFINITY;
    int b0 = 0, b1 = 0;

    for (int c = 0; c < K_CODES; c += 64) {
        __syncthreads();
        {   // stage 64 codes = 1024 float4, 8 per thread
            const float4* E4 = (const float4*)E + (size_t)c * 16;
#pragma unroll
            for (int i = 0; i < 8; ++i)
                se4[threadIdx.x + 128 * i] = E4[threadIdx.x + 128 * i];
            if (threadIdx.x < 64) sn[threadIdx.x] = enorm[c + threadIdx.x];
        }
        __syncthreads();

        for (int k = 0; k < 64; ++k) {
            const float4* er = se4 + k * 16;
            float a0 = 0.f, a1 = 0.f, a2 = 0.f, a3 = 0.f;
            float c0 = 0.f, c1 = 0.f, c2 = 0.f, c3 = 0.f;
#pragma unroll
            for (int i = 0; i < 16; ++i) {
                float4 ev = er[i];
                a0 += zr0[i].x * ev.x; a1 += zr0[i].y * ev.y;
                a2 += zr0[i].z * ev.z; a3 += zr0[i].w * ev.w;
                c0 += zr1[i].x * ev.x; c1 += zr1[i].y * ev.y;
                c2 += zr1[i].z * ev.z; c3 += zr1[i].w * ev.w;
            }
            float s0 = sn[k] - 2.f * ((a0 + a1) + (a2 + a3));
            float s1 = sn[k] - 2.f * ((c0 + c1) + (c2 + c3));
            if (s0 < best0) { best0 = s0; b0 = c + k; }
            if (s1 < best1) { best1 = s1; b1 = c + k; }
        }
    }

    out_idx_f[row0] = (float)b0;
    out_idx_f[row1] = (float)b1;
    atomicAdd(&counts[b0], 1.0f);
    atomicAdd(&counts[b1], 1.0f);
}

// One block of 1024: new_cluster_size, n, cs, and exclusive prefix sum of
// counts -> start/cursor arrays for the counting sort.
__global__ __launch_bounds__(1024) void scan_kernel(const float* __restrict__ cluster_size,
                                                    const float* __restrict__ counts,
                                                    float* __restrict__ ncs_out,
                                                    float* __restrict__ cs_ws,
                                                    int* __restrict__ start,
                                                    int* __restrict__ cursor) {
    int k = threadIdx.x;
    float cf = counts[k];
    float ncs = cluster_size[k] * DECAYF + OMDF * cf;
    ncs_out[k] = ncs;

    __shared__ float red[1024];
    __shared__ int pfx[1024];
    red[k] = ncs;
    pfx[k] = (int)cf;
    __syncthreads();
    for (int st = 512; st > 0; st >>= 1) {
        if (k < st) red[k] += red[k + st];
        __syncthreads();
    }
    float n = red[0];
    cs_ws[k] = (ncs + EPSF) / (n + (float)K_CODES * EPSF) * n;

    // Hillis-Steele inclusive scan on counts
    for (int off = 1; off < 1024; off <<= 1) {
        int add = (k >= off) ? pfx[k - off] : 0;
        __syncthreads();
        pfx[k] += add;
        __syncthreads();
    }
    int excl = pfx[k] - (int)cf;
    start[k] = excl;
    cursor[k] = excl;
}

__global__ __launch_bounds__(256) void scatter_kernel(const float* __restrict__ idx_f,
                                                      int* __restrict__ cursor,
                                                      int* __restrict__ order) {
    int row = blockIdx.x * 256 + threadIdx.x;
    int k = (int)idx_f[row];
    int p = atomicAdd(&cursor[k], 1);
    order[p] = row;
}

// One block (4 waves) per code: accumulate segment sum over the code's rows
// (no atomics), write z_q for those rows, per-code SSE partial, and the fused
// new_ema / new_embeddings epilogue.
__global__ __launch_bounds__(256) void segsum_kernel(const float* __restrict__ z,
                                                     const float* __restrict__ E,
                                                     const float* __restrict__ ema,
                                                     const float* __restrict__ countsf,
                                                     const int* __restrict__ start,
                                                     const int* __restrict__ order,
                                                     const float* __restrict__ cs_ws,
                                                     float* __restrict__ zq_out,
                                                     float* __restrict__ newema_out,
                                                     float* __restrict__ newemb_out,
                                                     float* __restrict__ lossarr) {
    int k = blockIdx.x;
    int d = threadIdx.x & 63;
    int w = threadIdx.x >> 6;
    int base = start[k];
    int cnt = (int)countsf[k];
    float e_d = E[k * DIM + d];

    float sum = 0.f, sse = 0.f;
    for (int r = base + w; r < base + cnt; r += 4) {
        int row = order[r];                       // wave-uniform
        float zv = z[(size_t)row * DIM + d];      // coalesced 256B per row
        zq_out[(size_t)row * DIM + d] = e_d;      // coalesced store
        sum += zv;
        float df = zv - e_d;
        sse += df * df;
    }

    __shared__ float s_red[256];
    s_red[threadIdx.x] = sum;
    __syncthreads();
    if (w == 0) {
        float tot = s_red[d] + s_red[64 + d] + s_red[128 + d] + s_red[192 + d];
        float nes = ema[k * DIM + d] * DECAYF + OMDF * tot;
        newema_out[k * DIM + d] = nes;
        newemb_out[k * DIM + d] = nes / cs_ws[k];
    }
    __syncthreads();
    s_red[threadIdx.x] = sse;
    __syncthreads();
    for (int st = 128; st > 0; st >>= 1) {
        if (threadIdx.x < st) s_red[threadIdx.x] += s_red[threadIdx.x + st];
        __syncthreads();
    }
    if (threadIdx.x == 0) lossarr[k] = s_red[0];
}

__global__ __launch_bounds__(1024) void finalize_kernel(const float* __restrict__ lossarr,
                                                        float* __restrict__ loss_out) {
    __shared__ float red[1024];
    red[threadIdx.x] = lossarr[threadIdx.x];
    __syncthreads();
    for (int st = 512; st > 0; st >>= 1) {
        if (threadIdx.x < st) red[threadIdx.x] += red[threadIdx.x + st];
        __syncthreads();
    }
    if (threadIdx.x == 0)
        loss_out[0] = red[0] * (1.0f / ((float)N_PTS * (float)DIM));
}

extern "C" void kernel_launch(void* const* d_in, const int* in_sizes, int n_in,
                              void* d_out, int out_size, void* d_ws, size_t ws_size,
                              hipStream_t stream) {
    const float* z            = (const float*)d_in[0];
    const float* E            = (const float*)d_in[1];
    const float* cluster_size = (const float*)d_in[2];
    const float* ema          = (const float*)d_in[3];
    float* out = (float*)d_out;
    float* ws  = (float*)d_ws;

    // zero only the count accumulators (ws is poisoned 0xAA)
    hipMemsetAsync(ws + WS_COUNTS, 0, K_CODES * sizeof(float), stream);

    enorm_kernel<<<4, 256, 0, stream>>>(E, ws + WS_ENORM);

    argmin_kernel<<<N_PTS / 256, 128, 0, stream>>>(z, E, ws + WS_ENORM,
                                                   out + OUT_IDX,
                                                   ws + WS_COUNTS);

    scan_kernel<<<1, 1024, 0, stream>>>(cluster_size, ws + WS_COUNTS,
                                        out + OUT_NEWCS, ws + WS_CS,
                                        (int*)(ws + WS_START),
                                        (int*)(ws + WS_CURSOR));

    scatter_kernel<<<N_PTS / 256, 256, 0, stream>>>(out + OUT_IDX,
                                                    (int*)(ws + WS_CURSOR),
                                                    (int*)(ws + WS_ORDER));

    segsum_kernel<<<K_CODES, 256, 0, stream>>>(z, E, ema, ws + WS_COUNTS,
                                               (const int*)(ws + WS_START),
                                               (const int*)(ws + WS_ORDER),
                                               ws + WS_CS,
                                               out + OUT_ZQ,
                                               out + OUT_NEWEMA,
                                               out + OUT_NEWEMB,
                                               ws + WS_LOSSARR);

    finalize_kernel<<<1, 1024, 0, stream>>>(ws + WS_LOSSARR, out + OUT_LOSS);
}